// Round 1
// baseline (315.496 us; speedup 1.0000x reference)
//
#include <hip/hip_runtime.h>
#include <hip/hip_bf16.h>

// Qwen2 Vision Attention, MI355X bf16-MFMA pipeline.
// Shapes fixed by the harness: SEQ=4096, E=1280, H=16, D=80, 4 images of 1024.
#define SEQ 4096
#define EMB 1280
#define NH 16
#define HD 80
#define HDP 96          // head dim padded to 3*32 for 16x16x32 MFMA k-steps
#define NIMG 4
#define SEGLEN 1024

typedef __attribute__((ext_vector_type(8))) short bf16x8;
typedef __attribute__((ext_vector_type(4))) float f32x4;
typedef unsigned short u16;
typedef unsigned int u32;

__device__ __forceinline__ u16 f2b(float f) {
  union { float f; u32 u; } v; v.f = f;
  u32 r = (v.u + 0x7fffu + ((v.u >> 16) & 1u)) >> 16;  // RNE
  return (u16)r;
}

// ---------------- fp32 -> bf16 convert (vectorized) ----------------
__global__ void cvt_kernel(const float* __restrict__ src, u16* __restrict__ dst, int n4) {
  int i = blockIdx.x * blockDim.x + threadIdx.x;
  int stride = gridDim.x * blockDim.x;
  for (; i < n4; i += stride) {
    float4 v = reinterpret_cast<const float4*>(src)[i];
    ushort4 o;
    o.x = f2b(v.x); o.y = f2b(v.y); o.z = f2b(v.z); o.w = f2b(v.w);
    reinterpret_cast<ushort4*>(dst)[i] = o;
  }
}

// ---------------- bf16 B^T GEMM: C[M][N] = A[M][K] * B[N][K]^T + bias ----------------
// m97 structure: 128x128 tile, BK=32, 4 waves (2x2), each wave 64x64 = 4x4 frags,
// global_load_lds width 16 into linear LDS [128][32].
__global__ __launch_bounds__(256) void gemm_bt_kernel(
    const u16* __restrict__ A, const u16* __restrict__ B,
    const float* __restrict__ bias, float* __restrict__ C,
    int M, int N, int K)
{
  __shared__ __align__(16) u16 lA[128 * 32];
  __shared__ __align__(16) u16 lB[128 * 32];
  const int m0 = blockIdx.y * 128, n0 = blockIdx.x * 128;
  const int tid = threadIdx.x, wave = tid >> 6, lane = tid & 63;
  const int wr = wave >> 1, wc = wave & 1;
  const int lr = lane & 15, lg = lane >> 4;
  f32x4 acc[4][4] = {};
  for (int k0 = 0; k0 < K; k0 += 32) {
    __syncthreads();  // previous iter's frag reads done before overwrite
    #pragma unroll
    for (int p = 0; p < 2; ++p) {
      int base = (p * 4 + wave) * 1024;            // byte offset in LDS
      int elem = (base >> 1) + lane * 8;           // element index (HW adds lane*16B)
      int r = elem >> 5, c = elem & 31;
      __builtin_amdgcn_global_load_lds(
          (const __attribute__((address_space(1))) void*)(A + (size_t)(m0 + r) * K + k0 + c),
          (__attribute__((address_space(3))) void*)((char*)lA + base), 16, 0, 0);
      __builtin_amdgcn_global_load_lds(
          (const __attribute__((address_space(1))) void*)(B + (size_t)(n0 + r) * K + k0 + c),
          (__attribute__((address_space(3))) void*)((char*)lB + base), 16, 0, 0);
    }
    __syncthreads();  // compiler drains vmcnt before barrier -> data ready
    bf16x8 af[4], bfr[4];
    #pragma unroll
    for (int mr = 0; mr < 4; ++mr)
      af[mr] = *(const bf16x8*)&lA[(wr * 64 + mr * 16 + lr) * 32 + lg * 8];
    #pragma unroll
    for (int nr = 0; nr < 4; ++nr)
      bfr[nr] = *(const bf16x8*)&lB[(wc * 64 + nr * 16 + lr) * 32 + lg * 8];
    #pragma unroll
    for (int mr = 0; mr < 4; ++mr)
      #pragma unroll
      for (int nr = 0; nr < 4; ++nr)
        acc[mr][nr] = __builtin_amdgcn_mfma_f32_16x16x32_bf16(af[mr], bfr[nr], acc[mr][nr], 0, 0, 0);
  }
  // epilogue: C layout col=lane&15, row=(lane>>4)*4+reg  [m89-verified]
  #pragma unroll
  for (int nr = 0; nr < 4; ++nr) {
    int col = n0 + wc * 64 + nr * 16 + lr;
    float bv = bias[col];
    #pragma unroll
    for (int mr = 0; mr < 4; ++mr) {
      int row = m0 + wr * 64 + mr * 16 + lg * 4;
      #pragma unroll
      for (int j = 0; j < 4; ++j)
        C[(size_t)(row + j) * N + col] = acc[mr][nr][j] + bv;
    }
  }
}

// ---------------- RoPE + repack: qkv fp32 -> Qb/Kb [h][s][96] bf16, VT [h][d][s] bf16 ----
__global__ __launch_bounds__(256) void pack_rope_kernel(
    const float* __restrict__ qkvf, const float* __restrict__ cosb,
    const float* __restrict__ sinb, u16* __restrict__ Qb,
    u16* __restrict__ Kb, u16* __restrict__ VT)
{
  const int h = blockIdx.y;
  const int s0 = blockIdx.x * 64;
  const int t = threadIdx.x;
  __shared__ float vt[64][81];  // +1 pad: transposed read conflict-free
  for (int i = t; i < 64 * 80; i += 256) {
    int r = i / 80, c = i % 80;
    vt[r][c] = qkvf[(size_t)(s0 + r) * 3840 + 2560 + h * 80 + c];
  }
  for (int i = t; i < 64 * 40; i += 256) {
    int r = i / 40, d = i % 40;
    int s = s0 + r;
    const float* row = qkvf + (size_t)s * 3840;
    float c = cosb[s * 40 + d], sn = sinb[s * 40 + d];
    float q1 = row[h * 80 + d], q2 = row[h * 80 + 40 + d];
    float k1 = row[1280 + h * 80 + d], k2 = row[1280 + h * 80 + 40 + d];
    size_t off = ((size_t)h * SEQ + s) * HDP;
    Qb[off + d]      = f2b(q1 * c - q2 * sn);
    Qb[off + 40 + d] = f2b(q2 * c + q1 * sn);
    Kb[off + d]      = f2b(k1 * c - k2 * sn);
    Kb[off + 40 + d] = f2b(k2 * c + k1 * sn);
  }
  // zero the pad columns 80..95 (ws is poison 0xAA)
  for (int i = t; i < 64 * 16; i += 256) {
    int r = i / 16, c = 80 + (i % 16);
    size_t off = ((size_t)h * SEQ + s0 + r) * HDP + c;
    Qb[off] = 0; Kb[off] = 0;
  }
  __syncthreads();
  // V transpose out: 80 d-rows x 64 s, 16B-vector stores
  for (int i = t; i < 320; i += 256) {
    int d = i >> 2, sc = (i & 3) * 16;
    size_t obase = ((size_t)h * HD + d) * SEQ + s0 + sc;
    #pragma unroll
    for (int half = 0; half < 2; ++half) {
      union { u16 u[8]; uint4 v; } pk;
      #pragma unroll
      for (int j = 0; j < 8; ++j) pk.u[j] = f2b(vt[sc + half * 8 + j][d]);
      *reinterpret_cast<uint4*>(&VT[obase + half * 8]) = pk.v;
    }
  }
}

// ---------------- flash attention per (img, head, 64 q-rows) ----------------
// 4 waves x 16 q-rows; KV tiles of 64; online softmax; no mask needed
// (tiles never cross the 1024-aligned image boundaries).
__global__ __launch_bounds__(256) void attn_kernel(
    const u16* __restrict__ Qb, const u16* __restrict__ Kb,
    const u16* __restrict__ VT, u16* __restrict__ ctxb)
{
  const int h = blockIdx.y, img = blockIdx.z;
  const int q0 = img * SEGLEN + blockIdx.x * 64;
  const int tid = threadIdx.x, wave = tid >> 6, lane = tid & 63;
  const int lr = lane & 15, lg = lane >> 4;
  __shared__ __align__(16) u16 lK[64][104];      // stride 104: 2-way (free) on b128
  __shared__ __align__(16) u16 lV[80][72];       // stride 72: 2-way (free)
  __shared__ __align__(16) u16 lP[4][16][72];    // per-wave P roundtrip buffer
  const int qrow = q0 + wave * 16 + lr;
  bf16x8 qf[3];
  {
    const u16* qb = Qb + ((size_t)h * SEQ + qrow) * HDP;
    #pragma unroll
    for (int kk = 0; kk < 3; ++kk)
      qf[kk] = *(const bf16x8*)(qb + kk * 32 + lg * 8);
  }
  float m[4], l[4];
  f32x4 oacc[5] = {};
  #pragma unroll
  for (int r = 0; r < 4; ++r) { m[r] = -1e30f; l[r] = 0.f; }
  const float scale = 0.11180339887498949f;  // 80^-0.5
  for (int kt = 0; kt < SEGLEN / 64; ++kt) {
    const int kb = img * SEGLEN + kt * 64;
    __syncthreads();  // all waves done with previous K/V tile
    for (int i = tid; i < 64 * 12; i += 256) {
      int r = i / 12, c8 = (i % 12) * 8;
      *(bf16x8*)&lK[r][c8] = *(const bf16x8*)(Kb + ((size_t)h * SEQ + kb + r) * HDP + c8);
    }
    for (int i = tid; i < 80 * 8; i += 256) {
      int r = i / 8, c8 = (i % 8) * 8;
      *(bf16x8*)&lV[r][c8] = *(const bf16x8*)(VT + ((size_t)h * HD + r) * SEQ + kb + c8);
    }
    __syncthreads();
    // S = Q K^T  (A=Q rows, B-operand=K rows, both k-contiguous over padded d=96)
    f32x4 sf[4] = {};
    #pragma unroll
    for (int n = 0; n < 4; ++n)
      #pragma unroll
      for (int kk = 0; kk < 3; ++kk) {
        bf16x8 kf = *(const bf16x8*)&lK[n * 16 + lr][kk * 32 + lg * 8];
        sf[n] = __builtin_amdgcn_mfma_f32_16x16x32_bf16(qf[kk], kf, sf[n], 0, 0, 0);
      }
    // online softmax: rows = lg*4+r (per reg), cols spread over 16 lanes
    float rmax[4], rsum[4], alpha[4];
    #pragma unroll
    for (int r = 0; r < 4; ++r) {
      float v0 = fmaxf(fmaxf(sf[0][r], sf[1][r]), fmaxf(sf[2][r], sf[3][r])) * scale;
      #pragma unroll
      for (int x = 1; x < 16; x <<= 1) v0 = fmaxf(v0, __shfl_xor(v0, x));
      float mn = fmaxf(m[r], v0);
      alpha[r] = __expf(m[r] - mn);
      m[r] = mn;
      rsum[r] = 0.f;
    }
    #pragma unroll
    for (int n = 0; n < 4; ++n)
      #pragma unroll
      for (int r = 0; r < 4; ++r) {
        float p = __expf(sf[n][r] * scale - m[r]);
        sf[n][r] = p; rsum[r] += p;
      }
    #pragma unroll
    for (int r = 0; r < 4; ++r) {
      float s = rsum[r];
      #pragma unroll
      for (int x = 1; x < 16; x <<= 1) s += __shfl_xor(s, x);
      l[r] = l[r] * alpha[r] + s;
      #pragma unroll
      for (int nd = 0; nd < 5; ++nd) oacc[nd][r] *= alpha[r];
    }
    // P: C-layout -> LDS -> A-layout (same-wave dep; compiler orders via lgkmcnt)
    #pragma unroll
    for (int n = 0; n < 4; ++n)
      #pragma unroll
      for (int r = 0; r < 4; ++r)
        lP[wave][lg * 4 + r][n * 16 + lr] = f2b(sf[n][r]);
    #pragma unroll
    for (int kk = 0; kk < 2; ++kk) {
      bf16x8 pf = *(const bf16x8*)&lP[wave][lr][kk * 32 + lg * 8];
      #pragma unroll
      for (int nd = 0; nd < 5; ++nd) {
        bf16x8 vf = *(const bf16x8*)&lV[nd * 16 + lr][kk * 32 + lg * 8];
        oacc[nd] = __builtin_amdgcn_mfma_f32_16x16x32_bf16(pf, vf, oacc[nd], 0, 0, 0);
      }
    }
  }
  // epilogue: ctx[s][h*80+d] bf16
  #pragma unroll
  for (int r = 0; r < 4; ++r) {
    float inv = 1.f / l[r];
    int s = q0 + wave * 16 + lg * 4 + r;
    #pragma unroll
    for (int nd = 0; nd < 5; ++nd)
      ctxb[(size_t)s * EMB + h * HD + nd * 16 + lr] = f2b(oacc[nd][r] * inv);
  }
}

// ---------------- launcher ----------------
extern "C" void kernel_launch(void* const* d_in, const int* in_sizes, int n_in,
                              void* d_out, int out_size, void* d_ws, size_t ws_size,
                              hipStream_t stream)
{
  const float* x     = (const float*)d_in[0];
  // d_in[1] = cu_seqlens: fixed [0,1024,2048,3072,4096] by problem setup (hard-coded)
  const float* cosb  = (const float*)d_in[2];
  const float* sinb  = (const float*)d_in[3];
  const float* qkvw  = (const float*)d_in[4];
  const float* qkvb  = (const float*)d_in[5];
  const float* projw = (const float*)d_in[6];
  const float* projb = (const float*)d_in[7];
  float* out = (float*)d_out;

  char* ws = (char*)d_ws;
  size_t off = 0;
  auto alloc = [&](size_t bytes) {
    char* p = ws + off;
    off += (bytes + 255) & ~(size_t)255;
    return p;
  };
  u16*   xb   = (u16*)  alloc((size_t)SEQ * EMB * 2);        // 10.5 MB (reused as ctxb)
  u16*   wb   = (u16*)  alloc((size_t)3 * EMB * EMB * 2);    //  9.8 MB
  u16*   pwb  = (u16*)  alloc((size_t)EMB * EMB * 2);        //  3.3 MB
  float* qkvf = (float*)alloc((size_t)SEQ * 3 * EMB * 4);    // 62.9 MB
  u16*   Qb   = (u16*)  alloc((size_t)NH * SEQ * HDP * 2);   // 12.6 MB
  u16*   Kb   = (u16*)  alloc((size_t)NH * SEQ * HDP * 2);   // 12.6 MB
  u16*   VT   = (u16*)  alloc((size_t)NH * HD * SEQ * 2);    // 10.5 MB
  u16*   ctxb = xb;  // x no longer needed after QKV GEMM

  hipLaunchKernelGGL(cvt_kernel, dim3(1024), dim3(256), 0, stream, x, xb, SEQ * EMB / 4);
  hipLaunchKernelGGL(cvt_kernel, dim3(1024), dim3(256), 0, stream, qkvw, wb, 3 * EMB * EMB / 4);
  hipLaunchKernelGGL(cvt_kernel, dim3(512),  dim3(256), 0, stream, projw, pwb, EMB * EMB / 4);
  hipLaunchKernelGGL(gemm_bt_kernel, dim3(3 * EMB / 128, SEQ / 128), dim3(256), 0, stream,
                     xb, wb, qkvb, qkvf, SEQ, 3 * EMB, EMB);
  hipLaunchKernelGGL(pack_rope_kernel, dim3(SEQ / 64, NH), dim3(256), 0, stream,
                     qkvf, cosb, sinb, Qb, Kb, VT);
  hipLaunchKernelGGL(attn_kernel, dim3(SEGLEN / 64, NH, NIMG), dim3(256), 0, stream,
                     Qb, Kb, VT, ctxb);
  hipLaunchKernelGGL(gemm_bt_kernel, dim3(EMB / 128, SEQ / 128), dim3(256), 0, stream,
                     ctxb, pwb, projb, out, SEQ, EMB, EMB);
}

// Round 3
// 274.972 us; speedup vs baseline: 1.1474x; 1.1474x over previous
//
#include <hip/hip_runtime.h>
#include <hip/hip_bf16.h>

// Qwen2 Vision Attention, MI355X bf16-MFMA pipeline (round 3 = round 2 + ws guard pads).
// SEQ=4096, E=1280, H=16, D=80, 4 images of 1024.
#define SEQ 4096
#define EMB 1280
#define NH 16
#define HD 80
#define NIMG 4
#define SEGLEN 1024

typedef __attribute__((ext_vector_type(8))) short bf16x8;
typedef __attribute__((ext_vector_type(4))) float f32x4;
typedef __attribute__((ext_vector_type(16))) float f32x16;
typedef unsigned short u16;
typedef unsigned int u32;

__device__ __forceinline__ u16 f2b(float f) {
  union { float f; u32 u; } v; v.f = f;
  u32 r = (v.u + 0x7fffu + ((v.u >> 16) & 1u)) >> 16;  // RNE
  return (u16)r;
}
__device__ __forceinline__ float b2f(u16 u) {
  union { u32 i; float f; } v; v.i = ((u32)u) << 16; return v.f;
}
__device__ __forceinline__ u32 cvtpk(float a, float b) {
  u32 r; asm("v_cvt_pk_bf16_f32 %0, %1, %2" : "=v"(r) : "v"(a), "v"(b)); return r;
}

// ---------------- fp32 -> bf16 convert (vectorized) ----------------
__global__ void cvt_kernel(const float* __restrict__ src, u16* __restrict__ dst, int n4) {
  int i = blockIdx.x * blockDim.x + threadIdx.x;
  int stride = gridDim.x * blockDim.x;
  for (; i < n4; i += stride) {
    float4 v = reinterpret_cast<const float4*>(src)[i];
    ushort4 o;
    o.x = f2b(v.x); o.y = f2b(v.y); o.z = f2b(v.z); o.w = f2b(v.w);
    reinterpret_cast<ushort4*>(dst)[i] = o;
  }
}

// ---------------- bf16 B^T GEMM: C[M][N] = A[M][K] * B[N][K]^T + bias ----------------
// m97 structure: 128x128 tile, BK=32, 4 waves (2x2), global_load_lds width 16.
template<bool BF16OUT>
__global__ __launch_bounds__(256) void gemm_bt_kernel(
    const u16* __restrict__ A, const u16* __restrict__ B,
    const float* __restrict__ bias, void* __restrict__ Cout,
    int M, int N, int K)
{
  __shared__ __align__(16) u16 lA[128 * 32];
  __shared__ __align__(16) u16 lB[128 * 32];
  const int m0 = blockIdx.y * 128, n0 = blockIdx.x * 128;
  const int tid = threadIdx.x, wave = tid >> 6, lane = tid & 63;
  const int wr = wave >> 1, wc = wave & 1;
  const int lr = lane & 15, lg = lane >> 4;
  f32x4 acc[4][4] = {};
  for (int k0 = 0; k0 < K; k0 += 32) {
    __syncthreads();
    #pragma unroll
    for (int p = 0; p < 2; ++p) {
      int base = (p * 4 + wave) * 1024;            // byte offset in LDS
      int elem = (base >> 1) + lane * 8;           // element index (HW adds lane*16B)
      int r = elem >> 5, c = elem & 31;
      __builtin_amdgcn_global_load_lds(
          (const __attribute__((address_space(1))) void*)(A + (size_t)(m0 + r) * K + k0 + c),
          (__attribute__((address_space(3))) void*)((char*)lA + base), 16, 0, 0);
      __builtin_amdgcn_global_load_lds(
          (const __attribute__((address_space(1))) void*)(B + (size_t)(n0 + r) * K + k0 + c),
          (__attribute__((address_space(3))) void*)((char*)lB + base), 16, 0, 0);
    }
    __syncthreads();
    bf16x8 af[4], bfr[4];
    #pragma unroll
    for (int mr = 0; mr < 4; ++mr)
      af[mr] = *(const bf16x8*)&lA[(wr * 64 + mr * 16 + lr) * 32 + lg * 8];
    #pragma unroll
    for (int nr = 0; nr < 4; ++nr)
      bfr[nr] = *(const bf16x8*)&lB[(wc * 64 + nr * 16 + lr) * 32 + lg * 8];
    #pragma unroll
    for (int mr = 0; mr < 4; ++mr)
      #pragma unroll
      for (int nr = 0; nr < 4; ++nr)
        acc[mr][nr] = __builtin_amdgcn_mfma_f32_16x16x32_bf16(af[mr], bfr[nr], acc[mr][nr], 0, 0, 0);
  }
  #pragma unroll
  for (int nr = 0; nr < 4; ++nr) {
    int col = n0 + wc * 64 + nr * 16 + lr;
    float bv = bias[col];
    #pragma unroll
    for (int mr = 0; mr < 4; ++mr) {
      int row = m0 + wr * 64 + mr * 16 + lg * 4;
      #pragma unroll
      for (int j = 0; j < 4; ++j) {
        float v = acc[mr][nr][j] + bv;
        if constexpr (BF16OUT)
          ((u16*)Cout)[(size_t)(row + j) * N + col] = f2b(v);
        else
          ((float*)Cout)[(size_t)(row + j) * N + col] = v;
      }
    }
  }
}

// ---------------- RoPE + repack (bf16 in): Qb/Kb [h][s][80] bf16, VT [h][d][s] bf16 ----
// Q is pre-scaled by 80^-0.5 so attention scores come out of MFMA as final logits.
__global__ __launch_bounds__(256) void pack_rope_kernel(
    const u16* __restrict__ qkvb, const float* __restrict__ cosb,
    const float* __restrict__ sinb, u16* __restrict__ Qb,
    u16* __restrict__ Kb, u16* __restrict__ VT)
{
  const int h = blockIdx.y;
  const int s0 = blockIdx.x * 64;
  const int t = threadIdx.x;
  __shared__ u16 vt[64][88];  // stride 88: transposed read bank-spread
  for (int i = t; i < 64 * 10; i += 256) {
    int r = i / 10, c8 = (i % 10) * 8;
    *(bf16x8*)&vt[r][c8] = *(const bf16x8*)(qkvb + (size_t)(s0 + r) * 3840 + 2560 + h * 80 + c8);
  }
  const float scale = 0.11180339887498949f;  // 80^-0.5
  for (int i = t; i < 64 * 40; i += 256) {
    int r = i / 40, d = i % 40;
    int s = s0 + r;
    const u16* row = qkvb + (size_t)s * 3840 + h * 80;
    float c = cosb[s * 40 + d], sn = sinb[s * 40 + d];
    float q1 = b2f(row[d]),        q2 = b2f(row[40 + d]);
    float k1 = b2f(row[1280 + d]), k2 = b2f(row[1280 + 40 + d]);
    size_t off = ((size_t)h * SEQ + s) * HD;
    Qb[off + d]      = f2b((q1 * c - q2 * sn) * scale);
    Qb[off + 40 + d] = f2b((q2 * c + q1 * sn) * scale);
    Kb[off + d]      = f2b(k1 * c - k2 * sn);
    Kb[off + 40 + d] = f2b(k2 * c + k1 * sn);
  }
  __syncthreads();
  for (int i = t; i < 320; i += 256) {
    int d = i >> 2, sc = (i & 3) * 16;
    size_t obase = ((size_t)h * HD + d) * SEQ + s0 + sc;
    #pragma unroll
    for (int half = 0; half < 2; ++half) {
      union { u16 u[8]; uint4 v; } pk;
      #pragma unroll
      for (int j = 0; j < 8; ++j) pk.u[j] = vt[sc + half * 8 + j][d];
      *reinterpret_cast<uint4*>(&VT[obase + half * 8]) = pk.v;
    }
  }
}

// ---------------- flash attention: 4 waves x 32 q-rows, KVBLK=64, 32x32x16 MFMA ----
// Swapped QK^T (mfma(K,Q)) -> per-lane q column; softmax fully in-register;
// P->A-frag via cvt_pk + permlane32_swap (T12); defer-max THR=8 (T13);
// K/V LDS XOR-swizzled via pre-swizzled global_load_lds source (m173/m214).
__global__ __launch_bounds__(256) void attn_kernel(
    const u16* __restrict__ Qb, const u16* __restrict__ Kb,
    const u16* __restrict__ VT, u16* __restrict__ ctxb)
{
  const int h = blockIdx.y, img = blockIdx.z;
  const int q0 = img * SEGLEN + blockIdx.x * 128;
  const int tid = threadIdx.x, wave = tid >> 6, lane = tid & 63;
  const int l31 = lane & 31, lhi = lane >> 5;
  __shared__ __align__(16) u16 lK[64 * 128];   // [64 keys][128 bf16] swizzled, 16KB
  __shared__ __align__(16) u16 lV[96 * 64];    // [96 d][64 keys] swizzled, 12KB (rows 80..95 unused cols)
  // Q fragments: B-operand layout col=lane&31, k=8*(lane>>5)+j
  bf16x8 qf[5];
  {
    const u16* qp = Qb + ((size_t)h * SEQ + q0 + wave * 32 + l31) * HD;
    #pragma unroll
    for (int ks = 0; ks < 5; ++ks)
      qf[ks] = *(const bf16x8*)(qp + ks * 16 + lhi * 8);
  }
  f32x16 oacc[3] = {};
  float mst = -1e30f, lst = 0.f;
  for (int kt = 0; kt < SEGLEN / 64; ++kt) {
    const int kb = img * SEGLEN + kt * 64;
    __syncthreads();  // previous tile's reads done
    // stage K (16 x 1KB) + V (10 x 1KB); source pre-swizzled, LDS linear
    for (int i = wave; i < 26; i += 4) {
      if (i < 16) {
        int p = i * 1024 + lane * 16;
        int row = p >> 8, cb = p & 255;
        int cbl = cb ^ ((row & 7) << 4);
        const u16* src = Kb + ((size_t)h * SEQ + kb + row) * HD + (cbl >> 1);
        __builtin_amdgcn_global_load_lds(
            (const __attribute__((address_space(1))) void*)src,
            (__attribute__((address_space(3))) void*)((char*)lK + i * 1024), 16, 0, 0);
      } else {
        int p = (i - 16) * 1024 + lane * 16;
        int d = p >> 7, cb = p & 127;
        int cbl = cb ^ ((d & 7) << 4);
        const u16* src = VT + ((size_t)h * HD + d) * SEQ + kb + (cbl >> 1);
        __builtin_amdgcn_global_load_lds(
            (const __attribute__((address_space(1))) void*)src,
            (__attribute__((address_space(3))) void*)((char*)lV + (i - 16) * 1024), 16, 0, 0);
      }
    }
    __syncthreads();  // vmcnt drained -> tiles ready
    // S^T = K . Q^T : rows=keys, cols=q.  sf0: keys 0..31, sf1: keys 32..63
    f32x16 sf0 = {}, sf1 = {};
    #pragma unroll
    for (int ks = 0; ks < 5; ++ks) {
      int c = ks * 32 + lhi * 16;
      int r0 = l31, r1 = l31 + 32;
      bf16x8 kf0 = *(const bf16x8*)((const char*)lK + r0 * 256 + (c ^ ((r0 & 7) << 4)));
      sf0 = __builtin_amdgcn_mfma_f32_32x32x16_bf16(kf0, qf[ks], sf0, 0, 0, 0);
      bf16x8 kf1 = *(const bf16x8*)((const char*)lK + r1 * 256 + (c ^ ((r1 & 7) << 4)));
      sf1 = __builtin_amdgcn_mfma_f32_32x32x16_bf16(kf1, qf[ks], sf1, 0, 0, 0);
    }
    // online softmax (lane pair l / l+32 share q-row l&31, keep identical state)
    float pm = sf0[0];
    #pragma unroll
    for (int r = 1; r < 16; ++r) pm = fmaxf(pm, sf0[r]);
    #pragma unroll
    for (int r = 0; r < 16; ++r) pm = fmaxf(pm, sf1[r]);
    pm = fmaxf(pm, __shfl_xor(pm, 32));
    if (!__all(pm - mst <= 8.f)) {       // T13 defer-max
      float mn = fmaxf(mst, pm);
      float al = __expf(mst - mn);
      mst = mn;
      lst *= al;
      #pragma unroll
      for (int nd = 0; nd < 3; ++nd)
        #pragma unroll
        for (int r = 0; r < 16; ++r) oacc[nd][r] *= al;
    }
    float rs = 0.f;
    #pragma unroll
    for (int r = 0; r < 16; ++r) { float p = __expf(sf0[r] - mst); sf0[r] = p; rs += p; }
    #pragma unroll
    for (int r = 0; r < 16; ++r) { float p = __expf(sf1[r] - mst); sf1[r] = p; rs += p; }
    rs += __shfl_xor(rs, 32);
    lst += rs;
    // P -> bf16 A-frags (T12) + PV
    auto pv_half = [&](f32x16& s, int half) {
      #pragma unroll
      for (int kq = 0; kq < 2; ++kq) {
        int b = kq * 8;
        u32 c01 = cvtpk(s[b + 0], s[b + 1]);
        u32 c23 = cvtpk(s[b + 2], s[b + 3]);
        u32 c45 = cvtpk(s[b + 4], s[b + 5]);
        u32 c67 = cvtpk(s[b + 6], s[b + 7]);
        auto r02 = __builtin_amdgcn_permlane32_swap(c01, c45, false, false);
        auto r13 = __builtin_amdgcn_permlane32_swap(c23, c67, false, false);
        union { u32 u[4]; bf16x8 v; } pa;
        pa.u[0] = r02[0]; pa.u[1] = r13[0]; pa.u[2] = r02[1]; pa.u[3] = r13[1];
        int ks2 = half * 2 + kq;
        #pragma unroll
        for (int nd = 0; nd < 3; ++nd) {
          int d = l31 + nd * 32;
          bf16x8 vf = *(const bf16x8*)((const char*)lV + d * 128 +
                        ((ks2 * 32 + lhi * 16) ^ ((d & 7) << 4)));
          oacc[nd] = __builtin_amdgcn_mfma_f32_32x32x16_bf16(pa.v, vf, oacc[nd], 0, 0, 0);
        }
      }
    };
    pv_half(sf0, 0);
    pv_half(sf1, 1);
  }
  // epilogue: O[q][d], C-layout col=lane&31(=d), row=(r&3)+8*(r>>2)+4*lhi(=q)
  float linv = 1.f / lst;
  #pragma unroll
  for (int r = 0; r < 16; ++r) {
    int qr = (r & 3) + 8 * (r >> 2) + 4 * lhi;
    float lv = __shfl(linv, qr);   // lane qr holds state for q-row qr
    int s = q0 + wave * 32 + qr;
    size_t ro = (size_t)s * EMB + h * HD;
    ctxb[ro + l31]      = f2b(oacc[0][r] * lv);
    ctxb[ro + 32 + l31] = f2b(oacc[1][r] * lv);
    if (l31 < 16) ctxb[ro + 64 + l31] = f2b(oacc[2][r] * lv);
  }
}

// ---------------- launcher ----------------
extern "C" void kernel_launch(void* const* d_in, const int* in_sizes, int n_in,
                              void* d_out, int out_size, void* d_ws, size_t ws_size,
                              hipStream_t stream)
{
  const float* x     = (const float*)d_in[0];
  // d_in[1] = cu_seqlens: fixed [0,1024,2048,3072,4096] (hard-coded)
  const float* cosb  = (const float*)d_in[2];
  const float* sinb  = (const float*)d_in[3];
  const float* qkvw  = (const float*)d_in[4];
  const float* qkvb  = (const float*)d_in[5];
  const float* projw = (const float*)d_in[6];
  const float* projb = (const float*)d_in[7];
  float* out = (float*)d_out;

  char* ws = (char*)d_ws;
  size_t off = 0;
  auto alloc = [&](size_t bytes) {
    char* p = ws + off;
    off += (bytes + 4096 + 255) & ~(size_t)255;   // +4KB guard pad per buffer
    return p;
  };
  u16* xb    = (u16*)alloc((size_t)SEQ * EMB * 2);        // reused as ctxb
  u16* wb    = (u16*)alloc((size_t)3 * EMB * EMB * 2);
  u16* pwb   = (u16*)alloc((size_t)EMB * EMB * 2);
  u16* qkvbf = (u16*)alloc((size_t)SEQ * 3 * EMB * 2);    // bf16 qkv
  u16* Qbuf  = (u16*)alloc((size_t)NH * SEQ * HD * 2);
  u16* Kbuf  = (u16*)alloc((size_t)NH * SEQ * HD * 2);
  u16* VT    = (u16*)alloc((size_t)NH * HD * SEQ * 2);
  u16* ctxb  = xb;

  hipLaunchKernelGGL(cvt_kernel, dim3(1024), dim3(256), 0, stream, x, xb, SEQ * EMB / 4);
  hipLaunchKernelGGL(cvt_kernel, dim3(1024), dim3(256), 0, stream, qkvw, wb, 3 * EMB * EMB / 4);
  hipLaunchKernelGGL(cvt_kernel, dim3(512),  dim3(256), 0, stream, projw, pwb, EMB * EMB / 4);
  gemm_bt_kernel<true><<<dim3(3 * EMB / 128, SEQ / 128), 256, 0, stream>>>(
      xb, wb, qkvb, qkvbf, SEQ, 3 * EMB, EMB);
  hipLaunchKernelGGL(pack_rope_kernel, dim3(SEQ / 64, NH), dim3(256), 0, stream,
                     qkvbf, cosb, sinb, Qbuf, Kbuf, VT);
  hipLaunchKernelGGL(attn_kernel, dim3(SEGLEN / 128, NH, NIMG), dim3(256), 0, stream,
                     Qbuf, Kbuf, VT, ctxb);
  gemm_bt_kernel<false><<<dim3(EMB / 128, SEQ / 128), 256, 0, stream>>>(
      ctxb, pwb, projb, out, SEQ, EMB, EMB);
}

// Round 4
// 246.585 us; speedup vs baseline: 1.2795x; 1.1151x over previous
//
#include <hip/hip_runtime.h>
#include <hip/hip_bf16.h>

// Qwen2 Vision Attention, MI355X bf16-MFMA pipeline (round 4).
// GEMMs moved to 8-wave BM=256 counted-vmcnt pipelined template (T1+T2+T4+T5).
// SEQ=4096, E=1280, H=16, D=80, 4 images of 1024.
#define SEQ 4096
#define EMB 1280
#define NH 16
#define HD 80
#define NIMG 4
#define SEGLEN 1024

typedef __attribute__((ext_vector_type(8))) short bf16x8;
typedef __attribute__((ext_vector_type(4))) float f32x4;
typedef __attribute__((ext_vector_type(16))) float f32x16;
typedef unsigned short u16;
typedef unsigned int u32;

__device__ __forceinline__ u16 f2b(float f) {
  union { float f; u32 u; } v; v.f = f;
  u32 r = (v.u + 0x7fffu + ((v.u >> 16) & 1u)) >> 16;  // RNE
  return (u16)r;
}
__device__ __forceinline__ float b2f(u16 u) {
  union { u32 i; float f; } v; v.i = ((u32)u) << 16; return v.f;
}
__device__ __forceinline__ u32 cvtpk(float a, float b) {
  u32 r; asm("v_cvt_pk_bf16_f32 %0, %1, %2" : "=v"(r) : "v"(a), "v"(b)); return r;
}

// ---------------- fp32 -> bf16 convert (vectorized) ----------------
__global__ void cvt_kernel(const float* __restrict__ src, u16* __restrict__ dst, int n4) {
  int i = blockIdx.x * blockDim.x + threadIdx.x;
  int stride = gridDim.x * blockDim.x;
  for (; i < n4; i += stride) {
    float4 v = reinterpret_cast<const float4*>(src)[i];
    ushort4 o;
    o.x = f2b(v.x); o.y = f2b(v.y); o.z = f2b(v.z); o.w = f2b(v.w);
    reinterpret_cast<ushort4*>(dst)[i] = o;
  }
}

// ---------------- pipelined bf16 B^T GEMM: C[M][N] = A[M][K] * B[N][K]^T + bias ------
// BM=256, BN=NF*64, BK=64, 8 waves (2M x 4N), per-wave 128 x NF*16 output.
// Double-buffered swizzled LDS; counted vmcnt (stage t+2, drain t+1); raw s_barrier.
template<int NF, bool BF16OUT>
__global__ __launch_bounds__(512, 2) void gemm_pipe_kernel(
    const u16* __restrict__ A, const u16* __restrict__ B,
    const float* __restrict__ bias, void* __restrict__ Cout,
    int M, int N, int K)
{
  constexpr int BN = NF * 64;
  __shared__ __align__(16) u16 lA[2][256 * 64];      // 64 KB, rows 128B, swizzled
  __shared__ __align__(16) u16 lB[2][BN * 64];       // 32/64 KB

  // T1: bijective XCD-chunked block swizzle (m204)
  const int nwg = gridDim.x * gridDim.y;
  const int orig = blockIdx.y * gridDim.x + blockIdx.x;
  const int qq = nwg >> 3, rr = nwg & 7;
  const int xcd = orig & 7, loc = orig >> 3;
  const int wg = (xcd < rr ? xcd * (qq + 1) : rr * (qq + 1) + (xcd - rr) * qq) + loc;
  const int ty = wg / gridDim.x, tx = wg % gridDim.x;
  const int m0 = ty * 256, n0 = tx * BN;

  const int tid = threadIdx.x, wave = tid >> 6, lane = tid & 63;
  const int wm = wave >> 2, wn = wave & 3;
  const int lr = lane & 15, lg = lane >> 4;
  const int RM = wm * 128, RN = wn * (NF * 16);

  // stage K-tile t into buffer c: LDS linear dest, inverse-swizzled global source.
  // LDS[row][cb] = G[row][cb ^ ((row&7)<<4)]  (byte cols within the 128B row)
  auto stage = [&](int c, int t) {
    const int k0 = t * 64;
    const int base = wave * 1024 + lane * 16;
    #pragma unroll
    for (int qc = 0; qc < 4; ++qc) {
      int p = qc * 8192 + base;
      int row = p >> 7, cb = p & 127;
      int cbs = cb ^ ((row & 7) << 4);
      __builtin_amdgcn_global_load_lds(
        (const __attribute__((address_space(1))) void*)(A + (size_t)(m0 + row) * K + k0 + (cbs >> 1)),
        (__attribute__((address_space(3))) void*)((char*)&lA[c][0] + qc * 8192 + wave * 1024),
        16, 0, 0);
    }
    #pragma unroll
    for (int qc = 0; qc < NF; ++qc) {
      int p = qc * 8192 + base;
      int row = p >> 7, cb = p & 127;
      int cbs = cb ^ ((row & 7) << 4);
      __builtin_amdgcn_global_load_lds(
        (const __attribute__((address_space(1))) void*)(B + (size_t)(n0 + row) * K + k0 + (cbs >> 1)),
        (__attribute__((address_space(3))) void*)((char*)&lB[c][0] + qc * 8192 + wave * 1024),
        16, 0, 0);
    }
  };

  f32x4 acc[8][NF] = {};

  // prologue: stage tiles 0 and 1; drain tile 0 only (counted), barrier.
  stage(0, 0);
  stage(1, 1);
  if constexpr (NF == 4) asm volatile("s_waitcnt vmcnt(8)" ::: "memory");
  else                   asm volatile("s_waitcnt vmcnt(6)" ::: "memory");
  __builtin_amdgcn_s_barrier();
  asm volatile("" ::: "memory");

  const int NT = K >> 6;
  const int swz = (lr & 7) << 4;
  for (int t = 0; t < NT; ++t) {
    const int c = t & 1;
    const char* lAc = (const char*)&lA[c][0];
    const char* lBc = (const char*)&lB[c][0];
    #pragma unroll
    for (int s = 0; s < 2; ++s) {
      const int cbyte = s * 64 + lg * 16;
      bf16x8 bfv[NF], afv[8];
      #pragma unroll
      for (int n = 0; n < NF; ++n)
        bfv[n] = *(const bf16x8*)(lBc + (RN + n * 16 + lr) * 128 + (cbyte ^ swz));
      #pragma unroll
      for (int m = 0; m < 8; ++m)
        afv[m] = *(const bf16x8*)(lAc + (RM + m * 16 + lr) * 128 + (cbyte ^ swz));
      __builtin_amdgcn_s_setprio(1);
      #pragma unroll
      for (int m = 0; m < 8; ++m)
        #pragma unroll
        for (int n = 0; n < NF; ++n)
          acc[m][n] = __builtin_amdgcn_mfma_f32_16x16x32_bf16(afv[m], bfv[n], acc[m][n], 0, 0, 0);
      __builtin_amdgcn_s_setprio(0);
    }
    if (t + 1 < NT) {
      __builtin_amdgcn_s_barrier();      // WAR: all waves done reading buf c
      asm volatile("" ::: "memory");
      if (t + 2 < NT) {
        stage(c, t + 2);                 // overwrite buf c with tile t+2
        if constexpr (NF == 4) asm volatile("s_waitcnt vmcnt(8)" ::: "memory");
        else                   asm volatile("s_waitcnt vmcnt(6)" ::: "memory");
      } else {
        asm volatile("s_waitcnt vmcnt(0)" ::: "memory");
      }
      __builtin_amdgcn_s_barrier();      // RAW: tile t+1 visible to all waves
      asm volatile("" ::: "memory");
      __builtin_amdgcn_sched_barrier(0);
    }
  }

  // epilogue: C layout col=lane&15 (from B-frag rows), row=(lane>>4)*4+j (from A-frag rows)
  #pragma unroll
  for (int n = 0; n < NF; ++n) {
    int col = n0 + RN + n * 16 + lr;
    float bv = bias[col];
    #pragma unroll
    for (int m = 0; m < 8; ++m) {
      int row = m0 + RM + m * 16 + lg * 4;
      #pragma unroll
      for (int j = 0; j < 4; ++j) {
        float v = acc[m][n][j] + bv;
        if constexpr (BF16OUT)
          ((u16*)Cout)[(size_t)(row + j) * N + col] = f2b(v);
        else
          ((float*)Cout)[(size_t)(row + j) * N + col] = v;
      }
    }
  }
}

// ---------------- RoPE + repack (bf16 in): Qb/Kb [h][s][80] bf16, VT [h][d][s] bf16 ----
// Q is pre-scaled by 80^-0.5 so attention scores come out of MFMA as final logits.
__global__ __launch_bounds__(256) void pack_rope_kernel(
    const u16* __restrict__ qkvb, const float* __restrict__ cosb,
    const float* __restrict__ sinb, u16* __restrict__ Qb,
    u16* __restrict__ Kb, u16* __restrict__ VT)
{
  const int h = blockIdx.y;
  const int s0 = blockIdx.x * 64;
  const int t = threadIdx.x;
  __shared__ u16 vt[64][88];  // stride 88: transposed read bank-spread
  for (int i = t; i < 64 * 10; i += 256) {
    int r = i / 10, c8 = (i % 10) * 8;
    *(bf16x8*)&vt[r][c8] = *(const bf16x8*)(qkvb + (size_t)(s0 + r) * 3840 + 2560 + h * 80 + c8);
  }
  const float scale = 0.11180339887498949f;  // 80^-0.5
  for (int i = t; i < 64 * 40; i += 256) {
    int r = i / 40, d = i % 40;
    int s = s0 + r;
    const u16* row = qkvb + (size_t)s * 3840 + h * 80;
    float c = cosb[s * 40 + d], sn = sinb[s * 40 + d];
    float q1 = b2f(row[d]),        q2 = b2f(row[40 + d]);
    float k1 = b2f(row[1280 + d]), k2 = b2f(row[1280 + 40 + d]);
    size_t off = ((size_t)h * SEQ + s) * HD;
    Qb[off + d]      = f2b((q1 * c - q2 * sn) * scale);
    Qb[off + 40 + d] = f2b((q2 * c + q1 * sn) * scale);
    Kb[off + d]      = f2b(k1 * c - k2 * sn);
    Kb[off + 40 + d] = f2b(k2 * c + k1 * sn);
  }
  __syncthreads();
  for (int i = t; i < 320; i += 256) {
    int d = i >> 2, sc = (i & 3) * 16;
    size_t obase = ((size_t)h * HD + d) * SEQ + s0 + sc;
    #pragma unroll
    for (int half = 0; half < 2; ++half) {
      union { u16 u[8]; uint4 v; } pk;
      #pragma unroll
      for (int j = 0; j < 8; ++j) pk.u[j] = vt[sc + half * 8 + j][d];
      *reinterpret_cast<uint4*>(&VT[obase + half * 8]) = pk.v;
    }
  }
}

// ---------------- flash attention: 4 waves x 32 q-rows, KVBLK=64, 32x32x16 MFMA ----
// Swapped QK^T (mfma(K,Q)); softmax in-register; T12 cvt_pk+permlane32_swap;
// T13 defer-max; K/V LDS XOR-swizzled via pre-swizzled global_load_lds source.
__global__ __launch_bounds__(256) void attn_kernel(
    const u16* __restrict__ Qb, const u16* __restrict__ Kb,
    const u16* __restrict__ VT, u16* __restrict__ ctxb)
{
  const int h = blockIdx.y, img = blockIdx.z;
  const int q0 = img * SEGLEN + blockIdx.x * 128;
  const int tid = threadIdx.x, wave = tid >> 6, lane = tid & 63;
  const int l31 = lane & 31, lhi = lane >> 5;
  __shared__ __align__(16) u16 lK[64 * 128];   // [64 keys][128 bf16] swizzled, 16KB
  __shared__ __align__(16) u16 lV[96 * 64];    // [96 d][64 keys] swizzled, 12KB
  bf16x8 qf[5];
  {
    const u16* qp = Qb + ((size_t)h * SEQ + q0 + wave * 32 + l31) * HD;
    #pragma unroll
    for (int ks = 0; ks < 5; ++ks)
      qf[ks] = *(const bf16x8*)(qp + ks * 16 + lhi * 8);
  }
  f32x16 oacc[3] = {};
  float mst = -1e30f, lst = 0.f;
  for (int kt = 0; kt < SEGLEN / 64; ++kt) {
    const int kb = img * SEGLEN + kt * 64;
    __syncthreads();
    for (int i = wave; i < 26; i += 4) {
      if (i < 16) {
        int p = i * 1024 + lane * 16;
        int row = p >> 8, cb = p & 255;
        int cbl = cb ^ ((row & 7) << 4);
        const u16* src = Kb + ((size_t)h * SEQ + kb + row) * HD + (cbl >> 1);
        __builtin_amdgcn_global_load_lds(
            (const __attribute__((address_space(1))) void*)src,
            (__attribute__((address_space(3))) void*)((char*)lK + i * 1024), 16, 0, 0);
      } else {
        int p = (i - 16) * 1024 + lane * 16;
        int d = p >> 7, cb = p & 127;
        int cbl = cb ^ ((d & 7) << 4);
        const u16* src = VT + ((size_t)h * HD + d) * SEQ + kb + (cbl >> 1);
        __builtin_amdgcn_global_load_lds(
            (const __attribute__((address_space(1))) void*)src,
            (__attribute__((address_space(3))) void*)((char*)lV + (i - 16) * 1024), 16, 0, 0);
      }
    }
    __syncthreads();
    f32x16 sf0 = {}, sf1 = {};
    #pragma unroll
    for (int ks = 0; ks < 5; ++ks) {
      int c = ks * 32 + lhi * 16;
      int r0 = l31, r1 = l31 + 32;
      bf16x8 kf0 = *(const bf16x8*)((const char*)lK + r0 * 256 + (c ^ ((r0 & 7) << 4)));
      sf0 = __builtin_amdgcn_mfma_f32_32x32x16_bf16(kf0, qf[ks], sf0, 0, 0, 0);
      bf16x8 kf1 = *(const bf16x8*)((const char*)lK + r1 * 256 + (c ^ ((r1 & 7) << 4)));
      sf1 = __builtin_amdgcn_mfma_f32_32x32x16_bf16(kf1, qf[ks], sf1, 0, 0, 0);
    }
    float pm = sf0[0];
    #pragma unroll
    for (int r = 1; r < 16; ++r) pm = fmaxf(pm, sf0[r]);
    #pragma unroll
    for (int r = 0; r < 16; ++r) pm = fmaxf(pm, sf1[r]);
    pm = fmaxf(pm, __shfl_xor(pm, 32));
    if (!__all(pm - mst <= 8.f)) {       // T13 defer-max
      float mn = fmaxf(mst, pm);
      float al = __expf(mst - mn);
      mst = mn;
      lst *= al;
      #pragma unroll
      for (int nd = 0; nd < 3; ++nd)
        #pragma unroll
        for (int r = 0; r < 16; ++r) oacc[nd][r] *= al;
    }
    float rs = 0.f;
    #pragma unroll
    for (int r = 0; r < 16; ++r) { float p = __expf(sf0[r] - mst); sf0[r] = p; rs += p; }
    #pragma unroll
    for (int r = 0; r < 16; ++r) { float p = __expf(sf1[r] - mst); sf1[r] = p; rs += p; }
    rs += __shfl_xor(rs, 32);
    lst += rs;
    auto pv_half = [&](f32x16& s, int half) {
      #pragma unroll
      for (int kq = 0; kq < 2; ++kq) {
        int b = kq * 8;
        u32 c01 = cvtpk(s[b + 0], s[b + 1]);
        u32 c23 = cvtpk(s[b + 2], s[b + 3]);
        u32 c45 = cvtpk(s[b + 4], s[b + 5]);
        u32 c67 = cvtpk(s[b + 6], s[b + 7]);
        auto r02 = __builtin_amdgcn_permlane32_swap(c01, c45, false, false);
        auto r13 = __builtin_amdgcn_permlane32_swap(c23, c67, false, false);
        union { u32 u[4]; bf16x8 v; } pa;
        pa.u[0] = r02[0]; pa.u[1] = r13[0]; pa.u[2] = r02[1]; pa.u[3] = r13[1];
        int ks2 = half * 2 + kq;
        #pragma unroll
        for (int nd = 0; nd < 3; ++nd) {
          int d = l31 + nd * 32;
          bf16x8 vf = *(const bf16x8*)((const char*)lV + d * 128 +
                        ((ks2 * 32 + lhi * 16) ^ ((d & 7) << 4)));
          oacc[nd] = __builtin_amdgcn_mfma_f32_32x32x16_bf16(pa.v, vf, oacc[nd], 0, 0, 0);
        }
      }
    };
    pv_half(sf0, 0);
    pv_half(sf1, 1);
  }
  float linv = 1.f / lst;
  #pragma unroll
  for (int r = 0; r < 16; ++r) {
    int qr = (r & 3) + 8 * (r >> 2) + 4 * lhi;
    float lv = __shfl(linv, qr);
    int s = q0 + wave * 32 + qr;
    size_t ro = (size_t)s * EMB + h * HD;
    ctxb[ro + l31]      = f2b(oacc[0][r] * lv);
    ctxb[ro + 32 + l31] = f2b(oacc[1][r] * lv);
    if (l31 < 16) ctxb[ro + 64 + l31] = f2b(oacc[2][r] * lv);
  }
}

// ---------------- launcher ----------------
extern "C" void kernel_launch(void* const* d_in, const int* in_sizes, int n_in,
                              void* d_out, int out_size, void* d_ws, size_t ws_size,
                              hipStream_t stream)
{
  const float* x     = (const float*)d_in[0];
  // d_in[1] = cu_seqlens: fixed [0,1024,2048,3072,4096] (hard-coded)
  const float* cosb  = (const float*)d_in[2];
  const float* sinb  = (const float*)d_in[3];
  const float* qkvw  = (const float*)d_in[4];
  const float* qkvb  = (const float*)d_in[5];
  const float* projw = (const float*)d_in[6];
  const float* projb = (const float*)d_in[7];
  float* out = (float*)d_out;

  char* ws = (char*)d_ws;
  size_t off = 0;
  auto alloc = [&](size_t bytes) {
    char* p = ws + off;
    off += (bytes + 4096 + 255) & ~(size_t)255;   // +4KB guard pad per buffer
    return p;
  };
  u16* xb    = (u16*)alloc((size_t)SEQ * EMB * 2);        // reused as ctxb
  u16* wb    = (u16*)alloc((size_t)3 * EMB * EMB * 2);
  u16* pwb   = (u16*)alloc((size_t)EMB * EMB * 2);
  u16* qkvbf = (u16*)alloc((size_t)SEQ * 3 * EMB * 2);    // bf16 qkv
  u16* Qbuf  = (u16*)alloc((size_t)NH * SEQ * HD * 2);
  u16* Kbuf  = (u16*)alloc((size_t)NH * SEQ * HD * 2);
  u16* VT    = (u16*)alloc((size_t)NH * HD * SEQ * 2);
  u16* ctxb  = xb;

  hipLaunchKernelGGL(cvt_kernel, dim3(1024), dim3(256), 0, stream, x, xb, SEQ * EMB / 4);
  hipLaunchKernelGGL(cvt_kernel, dim3(1024), dim3(256), 0, stream, qkvw, wb, 3 * EMB * EMB / 4);
  hipLaunchKernelGGL(cvt_kernel, dim3(512),  dim3(256), 0, stream, projw, pwb, EMB * EMB / 4);
  // QKV: M=4096, N=3840, K=1280; BN=256 -> grid 15 x 16 = 240 blocks
  gemm_pipe_kernel<4, true><<<dim3(3 * EMB / 256, SEQ / 256), 512, 0, stream>>>(
      xb, wb, qkvb, qkvbf, SEQ, 3 * EMB, EMB);
  hipLaunchKernelGGL(pack_rope_kernel, dim3(SEQ / 64, NH), dim3(256), 0, stream,
                     qkvbf, cosb, sinb, Qbuf, Kbuf, VT);
  hipLaunchKernelGGL(attn_kernel, dim3(SEGLEN / 128, NH, NIMG), dim3(256), 0, stream,
                     Qbuf, Kbuf, VT, ctxb);
  // proj: M=4096, N=1280, K=1280; BN=128 -> grid 10 x 16 = 160 blocks
  gemm_pipe_kernel<2, false><<<dim3(EMB / 128, SEQ / 256), 512, 0, stream>>>(
      ctxb, pwb, projb, out, SEQ, EMB, EMB);
}